// Round 11
// baseline (101550.818 us; speedup 1.0000x reference)
//
#include <hip/hip_runtime.h>

#define B_  64
#define T_  2048
#define I_  128
#define H_  256
#define G4  1024   // 4*H
#define TC  128    // timestep chunk

#define HC  12     // W chunks register-resident (48 dw/thread, safe under cap)
#define MC  9      // W chunks LDS-resident (147 KB/block)
#define SC  11     // W chunks streamed from L2 each step (176 KB/step/block)

typedef float    f32x4 __attribute__((ext_vector_type(4)));
typedef _Float16 f16x8 __attribute__((ext_vector_type(8)));
typedef _Float16 f16x2 __attribute__((ext_vector_type(2)));

__device__ __forceinline__ float dot2f(unsigned w, unsigned h, float acc) {
#if __has_builtin(__builtin_amdgcn_fdot2)
  return __builtin_amdgcn_fdot2(__builtin_bit_cast(f16x2, w),
                                __builtin_bit_cast(f16x2, h), acc, false);
#else
  f16x2 a = __builtin_bit_cast(f16x2, w), b = __builtin_bit_cast(f16x2, h);
  return acc + (float)a[0] * (float)b[0] + (float)a[1] * (float)b[1];
#endif
}

__device__ __forceinline__ unsigned short h16bits(float f) {
  return __builtin_bit_cast(unsigned short, (_Float16)f);
}
__device__ __forceinline__ float sigm(float x) { return 1.f / (1.f + __expf(-x)); }
__device__ __forceinline__ float tanh_fast(float x) { return 2.f / (1.f + __expf(-2.f * x)) - 1.f; }

// ---------------- prep kernels ----------------

// W_hh [1024][256] f32 -> wall[c4][row] uint4 of packed f16x2; chunk c4
// covers h-dims 8*c4 .. 8*c4+7.
__global__ void prep_w(const float* __restrict__ Whh, uint4* __restrict__ wall) {
  int idx = blockIdx.x * 256 + threadIdx.x;
  if (idx >= 32 * 1024) return;
  int c4 = idx >> 10, r = idx & 1023;
  unsigned q[4];
#pragma unroll
  for (int m = 0; m < 4; m++) {
    int kd = 4 * c4 + m;
    unsigned lo = h16bits(Whh[r * 256 + 2 * kd]);
    unsigned hi = h16bits(Whh[r * 256 + 2 * kd + 1]);
    q[m] = lo | (hi << 16);
  }
  wall[c4 * 1024 + r] = make_uint4(q[0], q[1], q[2], q[3]);
}

__global__ void prep_f16(const float* __restrict__ src, _Float16* __restrict__ dst, int n) {
  int i = blockIdx.x * 256 + threadIdx.x;
  if (i < n) dst[i] = (_Float16)src[i];
}

__global__ void prep_bias(const float* __restrict__ bi, const float* __restrict__ bh,
                          float* __restrict__ bias) {
  int i = blockIdx.x * 256 + threadIdx.x;
  if (i < G4) bias[i] = bi[i] + bh[i];
}

// ---------------- projection GEMM (f16 MFMA), xw stored f16 ----------------
template <int K, bool SRC_F32>
__global__ __launch_bounds__(256) void proj_kernel(const void* __restrict__ Asrc,
                                                   const _Float16* __restrict__ Wf,
                                                   const float* __restrict__ bias,
                                                   _Float16* __restrict__ xw, int t0) {
  const int m  = blockIdx.x;
  const int n0 = blockIdx.y * 64;
  const int tid = threadIdx.x;
  const int lane = tid & 63, wv = tid >> 6;

  __shared__ _Float16 As[64][40];
  __shared__ _Float16 Bs[64][40];

  f32x4 acc[4] = {f32x4{0,0,0,0}, f32x4{0,0,0,0}, f32x4{0,0,0,0}, f32x4{0,0,0,0}};

  const int r  = tid >> 2;
  const int kq = (tid & 3) * 8;
  const int r_g = m * 64 + r;
  const int b  = r_g >> 7;          // TC = 128
  const int tc = r_g & (TC - 1);
  long arow;
  if (SRC_F32) arow = (long)(b * T_ + t0 + tc) * K;
  else         arow = (long)r_g * K;

  for (int k0 = 0; k0 < K; k0 += 32) {
    if (SRC_F32) {
      const float* ap = (const float*)Asrc + arow + k0 + kq;
      float4 a0 = *(const float4*)ap;
      float4 a1 = *(const float4*)(ap + 4);
      _Float16* d = &As[r][kq];
      d[0] = (_Float16)a0.x; d[1] = (_Float16)a0.y; d[2] = (_Float16)a0.z; d[3] = (_Float16)a0.w;
      d[4] = (_Float16)a1.x; d[5] = (_Float16)a1.y; d[6] = (_Float16)a1.z; d[7] = (_Float16)a1.w;
    } else {
      const _Float16* ap = (const _Float16*)Asrc + arow + k0 + kq;
      *(uint4*)&As[r][kq] = *(const uint4*)ap;
    }
    *(uint4*)&Bs[r][kq] = *(const uint4*)(Wf + (long)(n0 + r) * K + k0 + kq);
    __syncthreads();

    f16x8 av = *(const f16x8*)&As[wv * 16 + (lane & 15)][(lane >> 4) * 8];
#pragma unroll
    for (int q = 0; q < 4; q++) {
      f16x8 bv = *(const f16x8*)&Bs[q * 16 + (lane & 15)][(lane >> 4) * 8];
      acc[q] = __builtin_amdgcn_mfma_f32_16x16x32_f16(av, bv, acc[q], 0, 0, 0);
    }
    __syncthreads();
  }

  const int row_in = wv * 16 + ((lane >> 4) << 2);
  const int col_in = lane & 15;
#pragma unroll
  for (int q = 0; q < 4; q++) {
#pragma unroll
    for (int i = 0; i < 4; i++) {
      int rr = m * 64 + row_in + i;
      int cc = n0 + q * 16 + col_in;
      xw[(long)rr * G4 + cc] = (_Float16)(acc[q][i] + bias[cc]);
    }
  }
}

// ---------------- recurrent scan ----------------
// One block (1024 threads, 16 waves) per (2 batches, layer-job). Thread t
// owns gate row G=t for BOTH batches -> W read once, used twice.
// __launch_bounds__(1024, 1): HIP's second arg acts like CUDA min-BLOCKS/CU;
// 1 block/CU = 16 waves/CU = 4 waves/SIMD -> RA budget 512/4 = 128 VGPR/lane.
// (r9 default assumed 2 blocks/CU -> 64 VGPR -> total spill, 4.9 GB/dispatch;
// r10's amdgpu_waves_per_eu attr lost to launch_bounds' derived value.)
// W tiers: 12 chunks in registers (48 dw/thread, safely under the proven
// 64-dw residency bound incl. in-flight loads), 9 chunks in LDS (147 KB),
// 11 chunks streamed from the shared L2-resident array each step (176 KB,
// amortized over 2 batches), issued in 3 groups to cap in-flight pressure.
// A launch carries TWO jobs (L0 chunk k, L1 chunk k-1) on disjoint blocks.

struct ScanJob {
  const _Float16* xw;      // [B*TC][1024] f16
  const uint4*    wall;    // [32][1024]
  const float*    mask;    // [B][256]
  float* hstate; float* cstate;
  _Float16* ychunk;        // layer0 output chunk (or null)
  float* out;              // layer1: d_out base (or null)
  float* hn; float* cn;    // last chunk only (or null)
  int t0; int valid;
};

#define C12(X) X(0) X(1) X(2) X(3) X(4) X(5) X(6) X(7) X(8) X(9) X(10) X(11)
#define C6A(X) X(0) X(1) X(2) X(3) X(4) X(5)
#define C6B(X) X(6) X(7) X(8) X(9) X(10) X(11)

#define LOADW(i) uint4 wR_##i = wall_p[(i) * 1024 + G];
#define PINW(i)  asm volatile("" : "+v"(wR_##i.x), "+v"(wR_##i.y), "+v"(wR_##i.z), "+v"(wR_##i.w));

#define DOTR(i) { uint4 h0 = hsA[i]; uint4 h1 = hsB[i]; \
  a0x = dot2f(wR_##i.x, h0.x, a0x); a1x = dot2f(wR_##i.x, h1.x, a1x); \
  a0y = dot2f(wR_##i.y, h0.y, a0y); a1y = dot2f(wR_##i.y, h1.y, a1y); \
  a0x = dot2f(wR_##i.z, h0.z, a0x); a1x = dot2f(wR_##i.z, h1.z, a1x); \
  a0y = dot2f(wR_##i.w, h0.w, a0y); a1y = dot2f(wR_##i.w, h1.w, a1y); }

#define DOTG(g, c) { uint4 h0 = hsA[c]; uint4 h1 = hsB[c]; \
  a0x = dot2f(g.x, h0.x, a0x); a1x = dot2f(g.x, h1.x, a1x); \
  a0y = dot2f(g.y, h0.y, a0y); a1y = dot2f(g.y, h1.y, a1y); \
  a0x = dot2f(g.z, h0.z, a0x); a1x = dot2f(g.z, h1.z, a1x); \
  a0y = dot2f(g.w, h0.w, a0y); a1y = dot2f(g.w, h1.w, a1y); }

__global__ __launch_bounds__(1024, 1) void scan_kernel(ScanJob j0, ScanJob j1) {
  const int nb = gridDim.x >> 1;            // blocks per job (B_/2)
  ScanJob j = (blockIdx.x < nb) ? j0 : j1;
  if (!j.valid) return;
  const int bb = (blockIdx.x < nb) ? blockIdx.x : blockIdx.x - nb;
  const int b0 = 2 * bb, b1 = 2 * bb + 1;
  const int t = threadIdx.x;                // 0..1023
  const int G = t;                          // own gate row

  __shared__ uint4 wmid[MC * 1024];                      // 147456 B
  __shared__ __align__(16) unsigned short hsm[2][256];   // h packed f16
  __shared__ float act[2][1024];                         // gate activations

  const uint4* wall_p = j.wall;

  // stage mid chunks into LDS (coalesced)
#pragma unroll
  for (int i = 0; i < MC; i++)
    wmid[i * 1024 + t] = wall_p[(HC + i) * 1024 + t];

  // register tier: 12 chunks x 1 row = 48 dwords, pinned
  C12(LOADW)
  C12(PINW)

  float c_reg = 0.f, h_reg = 0.f, mk = 0.f;
  if (t < 512) {
    const int b = 2 * bb + (t >> 8), jj = t & 255;
    c_reg = j.cstate[b * 256 + jj];
    mk    = j.mask[b * 256 + jj];
    hsm[t >> 8][jj] = h16bits(j.hstate[b * 256 + jj]);
  }
  __syncthreads();

  const uint4* hsA = (const uint4*)hsm[0];
  const uint4* hsB = (const uint4*)hsm[1];
  const _Float16* xwb0 = j.xw + (long)b0 * TC * G4;
  const _Float16* xwb1 = j.xw + (long)b1 * TC * G4;
  float xc0 = (float)xwb0[G], xc1 = (float)xwb1[G];
  float hm_prev = 0.f;

  for (int tc = 0; tc < TC; ++tc) {
    // prefetch next step's xw
    float nx0 = 0.f, nx1 = 0.f;
    if (tc + 1 < TC) {
      nx0 = (float)xwb0[(long)(tc + 1) * G4 + G];
      nx1 = (float)xwb1[(long)(tc + 1) * G4 + G];
    }

    // deferred output store for previous step (drain hides under the dots)
    if (t < 512 && tc > 0) {
      const int b = 2 * bb + (t >> 8), jj = t & 255;
      if (j.ychunk) j.ychunk[(b * TC + tc - 1) * H_ + jj] = (_Float16)hm_prev;
      else          j.out[(long)(b * T_ + j.t0 + tc - 1) * H_ + jj] = hm_prev;
    }

    float a0x = xc0, a0y = 0.f, a1x = xc1, a1y = 0.f;

    const uint4* wsp = wall_p + (HC + MC) * 1024;
    asm volatile("" : "+v"(wsp));   // opaque: no hoist across iterations

    // stream group 1: 4 loads in flight over register tier 0..5
    uint4 g0 = wsp[0 * 1024 + G];
    uint4 g1 = wsp[1 * 1024 + G];
    uint4 g2 = wsp[2 * 1024 + G];
    uint4 g3 = wsp[3 * 1024 + G];
    C6A(DOTR)
    DOTG(g0, HC + MC + 0) DOTG(g1, HC + MC + 1)
    DOTG(g2, HC + MC + 2) DOTG(g3, HC + MC + 3)

    // stream group 2: 4 loads in flight over register tier 6..11
    uint4 g4 = wsp[4 * 1024 + G];
    uint4 g5 = wsp[5 * 1024 + G];
    uint4 g6 = wsp[6 * 1024 + G];
    uint4 g7 = wsp[7 * 1024 + G];
    C6B(DOTR)
    DOTG(g4, HC + MC + 4) DOTG(g5, HC + MC + 5)
    DOTG(g6, HC + MC + 6) DOTG(g7, HC + MC + 7)

    // stream group 3: 3 loads in flight over the first LDS chunks
    uint4 g8 = wsp[8 * 1024 + G];
    uint4 g9 = wsp[9 * 1024 + G];
    uint4 gA = wsp[10 * 1024 + G];
#pragma unroll
    for (int m = 0; m < 4; m++) {
      uint4 tw = wmid[m * 1024 + G];
      DOTG(tw, HC + m)
    }
    DOTG(g8, HC + MC + 8) DOTG(g9, HC + MC + 9) DOTG(gA, HC + MC + 10)

    // remaining LDS tier
#pragma unroll
    for (int m = 4; m < MC; m++) {
      uint4 tw = wmid[m * 1024 + G];
      DOTG(tw, HC + m)
    }

    const float av0 = a0x + a0y;    // batch b0 pre-activation for row G
    const float av1 = a1x + a1y;    // batch b1
    const int gate = G >> 8;
    act[0][G] = (gate == 2) ? tanh_fast(av0) : sigm(av0);
    act[1][G] = (gate == 2) ? tanh_fast(av1) : sigm(av1);
    __syncthreads();

    if (t < 512) {
      const int b = t >> 8, jj = t & 255;
      float ci = act[b][jj], cf = act[b][jj + 256];
      float cg = act[b][jj + 512], co = act[b][jj + 768];
      c_reg = cf * c_reg + ci * cg;
      h_reg = co * tanh_fast(c_reg);
      hsm[b][jj] = h16bits(h_reg);
      hm_prev = h_reg * mk;
    }
    xc0 = nx0; xc1 = nx1;
    __syncthreads();
  }

  if (t < 512) {
    const int b = 2 * bb + (t >> 8), jj = t & 255;
    if (j.ychunk) j.ychunk[(b * TC + TC - 1) * H_ + jj] = (_Float16)hm_prev;
    else          j.out[(long)(b * T_ + j.t0 + TC - 1) * H_ + jj] = hm_prev;
    j.hstate[b * 256 + jj] = h_reg;
    j.cstate[b * 256 + jj] = c_reg;
    if (j.hn) { j.hn[b * 256 + jj] = h_reg; j.cn[b * 256 + jj] = c_reg; }
  }
}

// ---------------- host launch ----------------
extern "C" void kernel_launch(void* const* d_in, const int* in_sizes, int n_in,
                              void* d_out, int out_size, void* d_ws, size_t ws_size,
                              hipStream_t stream) {
  const float* x     = (const float*)d_in[0];
  const float* Wih0  = (const float*)d_in[1];
  const float* Whh0  = (const float*)d_in[2];
  const float* bih0  = (const float*)d_in[3];
  const float* bhh0  = (const float*)d_in[4];
  const float* mask0 = (const float*)d_in[5];
  const float* Wih1  = (const float*)d_in[6];
  const float* Whh1  = (const float*)d_in[7];
  const float* bih1  = (const float*)d_in[8];
  const float* bhh1  = (const float*)d_in[9];
  const float* mask1 = (const float*)d_in[10];

  float* out = (float*)d_out;
  float* hn  = out + (long)B_ * T_ * H_;   // [2][64][256]
  float* cn  = hn + 2 * B_ * H_;

  char* w = (char*)d_ws;
  uint4*    wall0  = (uint4*)w;      w += 512 << 10;   // [32][1024] uint4
  uint4*    wall1  = (uint4*)w;      w += 512 << 10;
  _Float16* wf0    = (_Float16*)w;   w += 256 << 10;
  _Float16* wf1    = (_Float16*)w;   w += 512 << 10;
  float*    bias0  = (float*)w;      w += 4 << 10;
  float*    bias1  = (float*)w;      w += 4 << 10;
  float*    h0s    = (float*)w;      w += 64 << 10;
  float*    c0s    = (float*)w;      w += 64 << 10;
  float*    h1s    = (float*)w;      w += 64 << 10;
  float*    c1s    = (float*)w;      w += 64 << 10;
  _Float16* xw0    = (_Float16*)w;   w += (long)B_ * TC * G4 * 2;   // 16 MB
  _Float16* xw1    = (_Float16*)w;   w += (long)B_ * TC * G4 * 2;   // 16 MB
  _Float16* ybuf   = (_Float16*)w;   w += (long)B_ * TC * H_ * 2;   // 4 MB

  hipMemsetAsync(h0s, 0, 4 * (64 << 10), stream);

  prep_w<<<128, 256, 0, stream>>>(Whh0, wall0);
  prep_w<<<128, 256, 0, stream>>>(Whh1, wall1);
  prep_f16<<<512, 256, 0, stream>>>(Wih0, wf0, G4 * I_);
  prep_f16<<<1024, 256, 0, stream>>>(Wih1, wf1, G4 * H_);
  prep_bias<<<4, 256, 0, stream>>>(bih0, bhh0, bias0);
  prep_bias<<<4, 256, 0, stream>>>(bih1, bhh1, bias1);

  const int nchunk = T_ / TC;  // 16
  for (int k = 0; k <= nchunk; k++) {
    if (k < nchunk) {
      proj_kernel<I_, true><<<dim3(B_ * TC / 64, G4 / 64), 256, 0, stream>>>(
          x, wf0, bias0, xw0, k * TC);
    }
    ScanJob j0, j1;
    // layer 0, chunk k
    j0.xw = xw0; j0.wall = wall0; j0.mask = mask0;
    j0.hstate = h0s; j0.cstate = c0s;
    j0.ychunk = ybuf; j0.out = nullptr;
    j0.hn = (k == nchunk - 1) ? hn : nullptr;
    j0.cn = (k == nchunk - 1) ? cn : nullptr;
    j0.t0 = k * TC; j0.valid = (k < nchunk);
    // layer 1, chunk k-1
    j1.xw = xw1; j1.wall = wall1; j1.mask = mask1;
    j1.hstate = h1s; j1.cstate = c1s;
    j1.ychunk = nullptr; j1.out = out;
    j1.hn = (k == nchunk) ? hn + B_ * H_ : nullptr;
    j1.cn = (k == nchunk) ? cn + B_ * H_ : nullptr;
    j1.t0 = (k - 1) * TC; j1.valid = (k >= 1);

    scan_kernel<<<B_, 1024, 0, stream>>>(j0, j1);   // 2*(B_/2) blocks

    if (k < nchunk) {
      proj_kernel<H_, false><<<dim3(B_ * TC / 64, G4 / 64), 256, 0, stream>>>(
          ybuf, wf1, bias1, xw1, k * TC);
    }
  }
}

// Round 12
// 9038.539 us; speedup vs baseline: 11.2353x; 11.2353x over previous
//
#include <hip/hip_runtime.h>

#define B_  64
#define T_  2048
#define I_  128
#define H_  256
#define G4  1024   // 4*H
#define TC  128    // timestep chunk

// W chunk tiers (chunk = uint4 per gate-row = 8 h-dims; 32 chunks total)
#define HC  8      // chunks 0..7   register-resident (64 dw/thread — PROVEN r7)
#define MC  9      // chunks 8..16  LDS-resident (147456 B)
// chunks 17..31 (15) streamed from L2 each step (240 KB/block, 2 batches)

typedef float    f32x4 __attribute__((ext_vector_type(4)));
typedef _Float16 f16x8 __attribute__((ext_vector_type(8)));
typedef _Float16 f16x2 __attribute__((ext_vector_type(2)));

__device__ __forceinline__ float dot2f(unsigned w, unsigned h, float acc) {
#if __has_builtin(__builtin_amdgcn_fdot2)
  return __builtin_amdgcn_fdot2(__builtin_bit_cast(f16x2, w),
                                __builtin_bit_cast(f16x2, h), acc, false);
#else
  f16x2 a = __builtin_bit_cast(f16x2, w), b = __builtin_bit_cast(f16x2, h);
  return acc + (float)a[0] * (float)b[0] + (float)a[1] * (float)b[1];
#endif
}

__device__ __forceinline__ unsigned short h16bits(float f) {
  return __builtin_bit_cast(unsigned short, (_Float16)f);
}
__device__ __forceinline__ float sigm(float x) { return 1.f / (1.f + __expf(-x)); }
__device__ __forceinline__ float tanh_fast(float x) { return 2.f / (1.f + __expf(-2.f * x)) - 1.f; }

// ---------------- prep kernels ----------------

__global__ void prep_w(const float* __restrict__ Whh, uint4* __restrict__ wall) {
  int idx = blockIdx.x * 256 + threadIdx.x;
  if (idx >= 32 * 1024) return;
  int c4 = idx >> 10, r = idx & 1023;
  unsigned q[4];
#pragma unroll
  for (int m = 0; m < 4; m++) {
    int kd = 4 * c4 + m;
    unsigned lo = h16bits(Whh[r * 256 + 2 * kd]);
    unsigned hi = h16bits(Whh[r * 256 + 2 * kd + 1]);
    q[m] = lo | (hi << 16);
  }
  wall[c4 * 1024 + r] = make_uint4(q[0], q[1], q[2], q[3]);
}

__global__ void prep_f16(const float* __restrict__ src, _Float16* __restrict__ dst, int n) {
  int i = blockIdx.x * 256 + threadIdx.x;
  if (i < n) dst[i] = (_Float16)src[i];
}

__global__ void prep_bias(const float* __restrict__ bi, const float* __restrict__ bh,
                          float* __restrict__ bias) {
  int i = blockIdx.x * 256 + threadIdx.x;
  if (i < G4) bias[i] = bi[i] + bh[i];
}

// ---------------- projection GEMM (f16 MFMA), xw stored f16 ----------------
template <int K, bool SRC_F32>
__global__ __launch_bounds__(256) void proj_kernel(const void* __restrict__ Asrc,
                                                   const _Float16* __restrict__ Wf,
                                                   const float* __restrict__ bias,
                                                   _Float16* __restrict__ xw, int t0) {
  const int m  = blockIdx.x;
  const int n0 = blockIdx.y * 64;
  const int tid = threadIdx.x;
  const int lane = tid & 63, wv = tid >> 6;

  __shared__ _Float16 As[64][40];
  __shared__ _Float16 Bs[64][40];

  f32x4 acc[4] = {f32x4{0,0,0,0}, f32x4{0,0,0,0}, f32x4{0,0,0,0}, f32x4{0,0,0,0}};

  const int r  = tid >> 2;
  const int kq = (tid & 3) * 8;
  const int r_g = m * 64 + r;
  const int b  = r_g >> 7;          // TC = 128
  const int tc = r_g & (TC - 1);
  long arow;
  if (SRC_F32) arow = (long)(b * T_ + t0 + tc) * K;
  else         arow = (long)r_g * K;

  for (int k0 = 0; k0 < K; k0 += 32) {
    if (SRC_F32) {
      const float* ap = (const float*)Asrc + arow + k0 + kq;
      float4 a0 = *(const float4*)ap;
      float4 a1 = *(const float4*)(ap + 4);
      _Float16* d = &As[r][kq];
      d[0] = (_Float16)a0.x; d[1] = (_Float16)a0.y; d[2] = (_Float16)a0.z; d[3] = (_Float16)a0.w;
      d[4] = (_Float16)a1.x; d[5] = (_Float16)a1.y; d[6] = (_Float16)a1.z; d[7] = (_Float16)a1.w;
    } else {
      const _Float16* ap = (const _Float16*)Asrc + arow + k0 + kq;
      *(uint4*)&As[r][kq] = *(const uint4*)ap;
    }
    *(uint4*)&Bs[r][kq] = *(const uint4*)(Wf + (long)(n0 + r) * K + k0 + kq);
    __syncthreads();

    f16x8 av = *(const f16x8*)&As[wv * 16 + (lane & 15)][(lane >> 4) * 8];
#pragma unroll
    for (int q = 0; q < 4; q++) {
      f16x8 bv = *(const f16x8*)&Bs[q * 16 + (lane & 15)][(lane >> 4) * 8];
      acc[q] = __builtin_amdgcn_mfma_f32_16x16x32_f16(av, bv, acc[q], 0, 0, 0);
    }
    __syncthreads();
  }

  const int row_in = wv * 16 + ((lane >> 4) << 2);
  const int col_in = lane & 15;
#pragma unroll
  for (int q = 0; q < 4; q++) {
#pragma unroll
    for (int i = 0; i < 4; i++) {
      int rr = m * 64 + row_in + i;
      int cc = n0 + q * 16 + col_in;
      xw[(long)rr * G4 + cc] = (_Float16)(acc[q][i] + bias[cc]);
    }
  }
}

// ---------------- recurrent scan ----------------
// One block (512 threads, 8 waves) per (2 batches, layer-job). Thread t owns
// gate rows r0=t, r1=t+512 for BOTH batches -> W read once, used twice.
//   t<256 (s=0): rows (i[j], g[j]), j=t   -> computes pig = sigm(i)*tanh(g)
//   t>=256 (s=1): rows (f[j], o[j]), j=t-256 -> owns c/h state for both batches
// 512-thr blocks at __launch_bounds__(512,1) are the PROVEN shape: r7 held a
// 64-dw pin at VGPR=88 with zero scratch. (1024-thr blocks are hard-capped at
// 64 VGPR by the backend's 2-workgroup heuristic — r9/r10/r11 all confirmed.)
// Tiers: reg chunks 0..7 (64 dw pinned), LDS 8..16 (147 KB), stream 17..31
// (240 KB/step from the shared L2-resident wall), issued in 4 groups of <=8
// loads interleaved with the reg/LDS dot blocks to hide L2 latency.
// A launch carries TWO jobs (L0 chunk k, L1 chunk k-1) on disjoint blocks.

struct ScanJob {
  const _Float16* xw;      // [B*TC][1024] f16
  const uint4*    wall;    // [32][1024]
  const float*    mask;    // [B][256]
  float* hstate; float* cstate;
  _Float16* ychunk;        // layer0 output chunk (or null)
  float* out;              // layer1: d_out base (or null)
  float* hn; float* cn;    // last chunk only (or null)
  int t0; int valid;
};

#define C8(X) X(0) X(1) X(2) X(3) X(4) X(5) X(6) X(7)

#define LOADW(i) \
  uint4 wA_##i = wall_p[(i) * 1024 + r0]; \
  uint4 wB_##i = wall_p[(i) * 1024 + r1];

#define PINW(i) \
  asm volatile("" : "+v"(wA_##i.x), "+v"(wA_##i.y), "+v"(wA_##i.z), "+v"(wA_##i.w), \
                    "+v"(wB_##i.x), "+v"(wB_##i.y), "+v"(wB_##i.z), "+v"(wB_##i.w));

// 16 dots per chunk: rows r0/r1 x batches 0/1
#define DOT2T(gA, gB, c) { uint4 hv0 = hsA[c]; uint4 hv1 = hsB[c]; \
  a00 = dot2f(gA.x, hv0.x, a00); a10 = dot2f(gA.x, hv1.x, a10); \
  a01 = dot2f(gB.x, hv0.x, a01); a11 = dot2f(gB.x, hv1.x, a11); \
  a00 = dot2f(gA.y, hv0.y, a00); a10 = dot2f(gA.y, hv1.y, a10); \
  a01 = dot2f(gB.y, hv0.y, a01); a11 = dot2f(gB.y, hv1.y, a11); \
  a00 = dot2f(gA.z, hv0.z, a00); a10 = dot2f(gA.z, hv1.z, a10); \
  a01 = dot2f(gB.z, hv0.z, a01); a11 = dot2f(gB.z, hv1.z, a11); \
  a00 = dot2f(gA.w, hv0.w, a00); a10 = dot2f(gA.w, hv1.w, a10); \
  a01 = dot2f(gB.w, hv0.w, a01); a11 = dot2f(gB.w, hv1.w, a11); }

#define DOTR(i)   DOT2T(wA_##i, wB_##i, i)
#define DOTL(c)   { uint4 tA = wmid[((c) - HC) * 1024 + r0]; \
                    uint4 tB = wmid[((c) - HC) * 1024 + r1]; \
                    DOT2T(tA, tB, c) }
#define LOADS(n, c) uint4 sA_##n = wsp[((c) - HC - MC) * 1024 + r0]; \
                    uint4 sB_##n = wsp[((c) - HC - MC) * 1024 + r1];
#define DOTS(n, c)  DOT2T(sA_##n, sB_##n, c)

__global__ __launch_bounds__(512, 1) void scan_kernel(ScanJob j0, ScanJob j1) {
  const int nb = gridDim.x >> 1;            // blocks per job (B_/2 = 32)
  ScanJob j = (blockIdx.x < nb) ? j0 : j1;
  if (!j.valid) return;
  const int bb = (blockIdx.x < nb) ? blockIdx.x : blockIdx.x - nb;
  const int b0 = 2 * bb, b1 = 2 * bb + 1;
  const int t = threadIdx.x;                // 0..511
  const int r0 = t, r1 = t + 512;
  const int s = t >> 8, jj = t & 255;

  __shared__ uint4 wmid[MC * 1024];                      // 147456 B
  __shared__ __align__(16) unsigned short hsm[2][256];   // h packed f16
  __shared__ float pig[2][256];                          // sigm(i)*tanh(g)

  const uint4* wall_p = j.wall;

  // stage LDS tier (coalesced)
#pragma unroll
  for (int i = 0; i < MC * 2; i++)
    wmid[i * 512 + t] = wall_p[HC * 1024 + i * 512 + t];

  // register tier: chunks 0..7, rows r0/r1 -> 64 dwords, pinned
  C8(LOADW)
  C8(PINW)

  float c0 = 0.f, c1 = 0.f, h0 = 0.f, h1 = 0.f, mk0 = 0.f, mk1 = 0.f;
  if (s == 1) {
    c0  = j.cstate[b0 * 256 + jj];
    c1  = j.cstate[b1 * 256 + jj];
    mk0 = j.mask[b0 * 256 + jj];
    mk1 = j.mask[b1 * 256 + jj];
    hsm[1][jj] = h16bits(j.hstate[b1 * 256 + jj]);
  } else {
    hsm[0][jj] = h16bits(j.hstate[b0 * 256 + jj]);
  }
  __syncthreads();

  const uint4* hsA = (const uint4*)hsm[0];
  const uint4* hsB = (const uint4*)hsm[1];
  const _Float16* xwb0 = j.xw + (long)b0 * TC * G4;
  const _Float16* xwb1 = j.xw + (long)b1 * TC * G4;
  float x00 = (float)xwb0[r0], x01 = (float)xwb0[r1];
  float x10 = (float)xwb1[r0], x11 = (float)xwb1[r1];
  float hm0p = 0.f, hm1p = 0.f;

  for (int tc = 0; tc < TC; ++tc) {
    // prefetch next step's xw (4 values)
    float n00 = 0.f, n01 = 0.f, n10 = 0.f, n11 = 0.f;
    if (tc + 1 < TC) {
      const long nx = (long)(tc + 1) * G4;
      n00 = (float)xwb0[nx + r0]; n01 = (float)xwb0[nx + r1];
      n10 = (float)xwb1[nx + r0]; n11 = (float)xwb1[nx + r1];
    }

    // deferred output stores for previous step (drain hides under the dots)
    if (s == 1 && tc > 0) {
      if (j.ychunk) {
        j.ychunk[(b0 * TC + tc - 1) * H_ + jj] = (_Float16)hm0p;
        j.ychunk[(b1 * TC + tc - 1) * H_ + jj] = (_Float16)hm1p;
      } else {
        j.out[(long)(b0 * T_ + j.t0 + tc - 1) * H_ + jj] = hm0p;
        j.out[(long)(b1 * T_ + j.t0 + tc - 1) * H_ + jj] = hm1p;
      }
    }

    float a00 = x00, a01 = x01, a10 = x10, a11 = x11;

    const uint4* wsp = wall_p + (HC + MC) * 1024;
    asm volatile("" : "+v"(wsp));   // opaque: no hoist across iterations

    // group A: issue 8 stream loads, cover with the register tier
    LOADS(0, 17) LOADS(1, 18) LOADS(2, 19) LOADS(3, 20)
    C8(DOTR)
    DOTS(0, 17) DOTS(1, 18)

    // group B in flight over the rest of A + LDS chunks
    LOADS(4, 21) LOADS(5, 22) LOADS(6, 23) LOADS(7, 24)
    DOTS(2, 19) DOTS(3, 20)
    DOTL(8) DOTL(9) DOTL(10)
    DOTS(4, 21) DOTS(5, 22)

    // group C
    LOADS(8, 25) LOADS(9, 26) LOADS(10, 27) LOADS(11, 28)
    DOTS(6, 23) DOTS(7, 24)
    DOTL(11) DOTL(12) DOTL(13)
    DOTS(8, 25) DOTS(9, 26)

    // group D
    LOADS(12, 29) LOADS(13, 30) LOADS(14, 31)
    DOTS(10, 27) DOTS(11, 28)
    DOTL(14) DOTL(15) DOTL(16)
    DOTS(12, 29) DOTS(13, 30) DOTS(14, 31)

    // combine: s=0 -> (a00,a01)=(i,g) etc.; s=1 -> (f,o)
    if (s == 0) {
      pig[0][jj] = sigm(a00) * tanh_fast(a01);
      pig[1][jj] = sigm(a10) * tanh_fast(a11);
    }
    __syncthreads();
    if (s == 1) {
      c0 = sigm(a00) * c0 + pig[0][jj];
      h0 = sigm(a01) * tanh_fast(c0);
      hsm[0][jj] = h16bits(h0);
      hm0p = h0 * mk0;
      c1 = sigm(a10) * c1 + pig[1][jj];
      h1 = sigm(a11) * tanh_fast(c1);
      hsm[1][jj] = h16bits(h1);
      hm1p = h1 * mk1;
    }
    x00 = n00; x01 = n01; x10 = n10; x11 = n11;
    __syncthreads();
  }

  if (s == 1) {
    if (j.ychunk) {
      j.ychunk[(b0 * TC + TC - 1) * H_ + jj] = (_Float16)hm0p;
      j.ychunk[(b1 * TC + TC - 1) * H_ + jj] = (_Float16)hm1p;
    } else {
      j.out[(long)(b0 * T_ + j.t0 + TC - 1) * H_ + jj] = hm0p;
      j.out[(long)(b1 * T_ + j.t0 + TC - 1) * H_ + jj] = hm1p;
    }
    j.hstate[b0 * 256 + jj] = h0; j.cstate[b0 * 256 + jj] = c0;
    j.hstate[b1 * 256 + jj] = h1; j.cstate[b1 * 256 + jj] = c1;
    if (j.hn) {
      j.hn[b0 * 256 + jj] = h0; j.cn[b0 * 256 + jj] = c0;
      j.hn[b1 * 256 + jj] = h1; j.cn[b1 * 256 + jj] = c1;
    }
  }
}

// ---------------- host launch ----------------
extern "C" void kernel_launch(void* const* d_in, const int* in_sizes, int n_in,
                              void* d_out, int out_size, void* d_ws, size_t ws_size,
                              hipStream_t stream) {
  const float* x     = (const float*)d_in[0];
  const float* Wih0  = (const float*)d_in[1];
  const float* Whh0  = (const float*)d_in[2];
  const float* bih0  = (const float*)d_in[3];
  const float* bhh0  = (const float*)d_in[4];
  const float* mask0 = (const float*)d_in[5];
  const float* Wih1  = (const float*)d_in[6];
  const float* Whh1  = (const float*)d_in[7];
  const float* bih1  = (const float*)d_in[8];
  const float* bhh1  = (const float*)d_in[9];
  const float* mask1 = (const float*)d_in[10];

  float* out = (float*)d_out;
  float* hn  = out + (long)B_ * T_ * H_;   // [2][64][256]
  float* cn  = hn + 2 * B_ * H_;

  char* w = (char*)d_ws;
  uint4*    wall0  = (uint4*)w;      w += 512 << 10;   // [32][1024] uint4
  uint4*    wall1  = (uint4*)w;      w += 512 << 10;
  _Float16* wf0    = (_Float16*)w;   w += 256 << 10;
  _Float16* wf1    = (_Float16*)w;   w += 512 << 10;
  float*    bias0  = (float*)w;      w += 4 << 10;
  float*    bias1  = (float*)w;      w += 4 << 10;
  float*    h0s    = (float*)w;      w += 64 << 10;
  float*    c0s    = (float*)w;      w += 64 << 10;
  float*    h1s    = (float*)w;      w += 64 << 10;
  float*    c1s    = (float*)w;      w += 64 << 10;
  _Float16* xw0    = (_Float16*)w;   w += (long)B_ * TC * G4 * 2;   // 16 MB
  _Float16* xw1    = (_Float16*)w;   w += (long)B_ * TC * G4 * 2;   // 16 MB
  _Float16* ybuf   = (_Float16*)w;   w += (long)B_ * TC * H_ * 2;   // 4 MB

  hipMemsetAsync(h0s, 0, 4 * (64 << 10), stream);

  prep_w<<<128, 256, 0, stream>>>(Whh0, wall0);
  prep_w<<<128, 256, 0, stream>>>(Whh1, wall1);
  prep_f16<<<512, 256, 0, stream>>>(Wih0, wf0, G4 * I_);
  prep_f16<<<1024, 256, 0, stream>>>(Wih1, wf1, G4 * H_);
  prep_bias<<<4, 256, 0, stream>>>(bih0, bhh0, bias0);
  prep_bias<<<4, 256, 0, stream>>>(bih1, bhh1, bias1);

  const int nchunk = T_ / TC;  // 16
  for (int k = 0; k <= nchunk; k++) {
    if (k < nchunk) {
      proj_kernel<I_, true><<<dim3(B_ * TC / 64, G4 / 64), 256, 0, stream>>>(
          x, wf0, bias0, xw0, k * TC);
    }
    ScanJob j0, j1;
    // layer 0, chunk k
    j0.xw = xw0; j0.wall = wall0; j0.mask = mask0;
    j0.hstate = h0s; j0.cstate = c0s;
    j0.ychunk = ybuf; j0.out = nullptr;
    j0.hn = (k == nchunk - 1) ? hn : nullptr;
    j0.cn = (k == nchunk - 1) ? cn : nullptr;
    j0.t0 = k * TC; j0.valid = (k < nchunk);
    // layer 1, chunk k-1
    j1.xw = xw1; j1.wall = wall1; j1.mask = mask1;
    j1.hstate = h1s; j1.cstate = c1s;
    j1.ychunk = nullptr; j1.out = out;
    j1.hn = (k == nchunk) ? hn + B_ * H_ : nullptr;
    j1.cn = (k == nchunk) ? cn + B_ * H_ : nullptr;
    j1.t0 = (k - 1) * TC; j1.valid = (k >= 1);

    scan_kernel<<<B_, 512, 0, stream>>>(j0, j1);   // 2 jobs x 32 blocks

    if (k < nchunk) {
      proj_kernel<H_, false><<<dim3(B_ * TC / 64, G4 / 64), 256, 0, stream>>>(
          ybuf, wf1, bias1, xw1, k * TC);
    }
  }
}

// Round 13
// 5338.251 us; speedup vs baseline: 19.0232x; 1.6932x over previous
//
#include <hip/hip_runtime.h>

#define B_  64
#define T_  2048
#define I_  128
#define H_  256
#define G4  1024   // 4*H
#define TC  128    // timestep chunk

// W chunk tiers (chunk = uint4 per gate-row = 8 h-dims; 32 chunks total)
#define HC  23     // chunks 0..22 register-resident (184 dw/thread @ (512,1))
#define MC  9      // chunks 23..31 LDS-resident (147456 B)  -> ZERO streaming

typedef float    f32x4 __attribute__((ext_vector_type(4)));
typedef _Float16 f16x8 __attribute__((ext_vector_type(8)));
typedef _Float16 f16x2 __attribute__((ext_vector_type(2)));

__device__ __forceinline__ float dot2f(unsigned w, unsigned h, float acc) {
#if __has_builtin(__builtin_amdgcn_fdot2)
  return __builtin_amdgcn_fdot2(__builtin_bit_cast(f16x2, w),
                                __builtin_bit_cast(f16x2, h), acc, false);
#else
  f16x2 a = __builtin_bit_cast(f16x2, w), b = __builtin_bit_cast(f16x2, h);
  return acc + (float)a[0] * (float)b[0] + (float)a[1] * (float)b[1];
#endif
}

__device__ __forceinline__ unsigned short h16bits(float f) {
  return __builtin_bit_cast(unsigned short, (_Float16)f);
}
__device__ __forceinline__ float sigm(float x) { return 1.f / (1.f + __expf(-x)); }
__device__ __forceinline__ float tanh_fast(float x) { return 2.f / (1.f + __expf(-2.f * x)) - 1.f; }

// ---------------- prep kernels ----------------

__global__ void prep_w(const float* __restrict__ Whh, uint4* __restrict__ wall) {
  int idx = blockIdx.x * 256 + threadIdx.x;
  if (idx >= 32 * 1024) return;
  int c4 = idx >> 10, r = idx & 1023;
  unsigned q[4];
#pragma unroll
  for (int m = 0; m < 4; m++) {
    int kd = 4 * c4 + m;
    unsigned lo = h16bits(Whh[r * 256 + 2 * kd]);
    unsigned hi = h16bits(Whh[r * 256 + 2 * kd + 1]);
    q[m] = lo | (hi << 16);
  }
  wall[c4 * 1024 + r] = make_uint4(q[0], q[1], q[2], q[3]);
}

__global__ void prep_f16(const float* __restrict__ src, _Float16* __restrict__ dst, int n) {
  int i = blockIdx.x * 256 + threadIdx.x;
  if (i < n) dst[i] = (_Float16)src[i];
}

__global__ void prep_bias(const float* __restrict__ bi, const float* __restrict__ bh,
                          float* __restrict__ bias) {
  int i = blockIdx.x * 256 + threadIdx.x;
  if (i < G4) bias[i] = bi[i] + bh[i];
}

// ---------------- projection GEMM (f16 MFMA), xw stored f16 ----------------
template <int K, bool SRC_F32>
__global__ __launch_bounds__(256) void proj_kernel(const void* __restrict__ Asrc,
                                                   const _Float16* __restrict__ Wf,
                                                   const float* __restrict__ bias,
                                                   _Float16* __restrict__ xw, int t0) {
  const int m  = blockIdx.x;
  const int n0 = blockIdx.y * 64;
  const int tid = threadIdx.x;
  const int lane = tid & 63, wv = tid >> 6;

  __shared__ _Float16 As[64][40];
  __shared__ _Float16 Bs[64][40];

  f32x4 acc[4] = {f32x4{0,0,0,0}, f32x4{0,0,0,0}, f32x4{0,0,0,0}, f32x4{0,0,0,0}};

  const int r  = tid >> 2;
  const int kq = (tid & 3) * 8;
  const int r_g = m * 64 + r;
  const int b  = r_g >> 7;          // TC = 128
  const int tc = r_g & (TC - 1);
  long arow;
  if (SRC_F32) arow = (long)(b * T_ + t0 + tc) * K;
  else         arow = (long)r_g * K;

  for (int k0 = 0; k0 < K; k0 += 32) {
    if (SRC_F32) {
      const float* ap = (const float*)Asrc + arow + k0 + kq;
      float4 a0 = *(const float4*)ap;
      float4 a1 = *(const float4*)(ap + 4);
      _Float16* d = &As[r][kq];
      d[0] = (_Float16)a0.x; d[1] = (_Float16)a0.y; d[2] = (_Float16)a0.z; d[3] = (_Float16)a0.w;
      d[4] = (_Float16)a1.x; d[5] = (_Float16)a1.y; d[6] = (_Float16)a1.z; d[7] = (_Float16)a1.w;
    } else {
      const _Float16* ap = (const _Float16*)Asrc + arow + k0 + kq;
      *(uint4*)&As[r][kq] = *(const uint4*)ap;
    }
    *(uint4*)&Bs[r][kq] = *(const uint4*)(Wf + (long)(n0 + r) * K + k0 + kq);
    __syncthreads();

    f16x8 av = *(const f16x8*)&As[wv * 16 + (lane & 15)][(lane >> 4) * 8];
#pragma unroll
    for (int q = 0; q < 4; q++) {
      f16x8 bv = *(const f16x8*)&Bs[q * 16 + (lane & 15)][(lane >> 4) * 8];
      acc[q] = __builtin_amdgcn_mfma_f32_16x16x32_f16(av, bv, acc[q], 0, 0, 0);
    }
    __syncthreads();
  }

  const int row_in = wv * 16 + ((lane >> 4) << 2);
  const int col_in = lane & 15;
#pragma unroll
  for (int q = 0; q < 4; q++) {
#pragma unroll
    for (int i = 0; i < 4; i++) {
      int rr = m * 64 + row_in + i;
      int cc = n0 + q * 16 + col_in;
      xw[(long)rr * G4 + cc] = (_Float16)(acc[q][i] + bias[cc]);
    }
  }
}

// ---------------- recurrent scan ----------------
// One block (512 threads, 8 waves) per (batch, layer-job). Thread t:
// p=t&255, s=t>>8; rows r0=p+s*256 (i or f), r1=r0+512 (g or o).
//   s=0 -> computes pig = sigm(i)*tanh(g);  s=1 -> (f,o) + owns c/h state.
// FULL W residency: 23 chunks pinned in registers (184 dw/thread — legal at
// __launch_bounds__(512,1): RA budget 256/lane; evidence r12 freely used 116,
// r2/r3 used 252 at (256,1)) + 9 chunks in LDS (147 KB). ZERO per-step
// streaming: per-step off-CU traffic = 2 xw loads + 1 output store/thread.
// NOTE (hard-won): the backend caps VGPRs to 512/(2*waves_per_block/4) unless
// launch_bounds' 2nd arg is 1 — waves_per_eu attrs are IGNORED (r8/r10/r11);
// 1024-thr blocks are hard-capped at 64 (r9-r11).
// A launch carries TWO jobs (L0 chunk k, L1 chunk k-1) on disjoint blocks.

struct ScanJob {
  const _Float16* xw;      // [B*TC][1024] f16
  const uint4*    wall;    // [32][1024]
  const float*    mask;    // [B][256]
  float* hstate; float* cstate;
  _Float16* ychunk;        // layer0 output chunk (or null)
  float* out;              // layer1: d_out base (or null)
  float* hn; float* cn;    // last chunk only (or null)
  int t0; int valid;
};

#define C23(X) X(0) X(1) X(2) X(3) X(4) X(5) X(6) X(7) X(8) X(9) X(10) X(11) \
               X(12) X(13) X(14) X(15) X(16) X(17) X(18) X(19) X(20) X(21) X(22)

#define LOADW(i) \
  uint4 wA_##i = wall_p[(i) * 1024 + r0]; \
  uint4 wB_##i = wall_p[(i) * 1024 + r1];

#define PINW(i) \
  asm volatile("" : "+v"(wA_##i.x), "+v"(wA_##i.y), "+v"(wA_##i.z), "+v"(wA_##i.w), \
                    "+v"(wB_##i.x), "+v"(wB_##i.y), "+v"(wB_##i.z), "+v"(wB_##i.w));

// 8 dots per chunk over 4 accumulator chains
#define DOT2(gA, gB, c) { uint4 hv = hs4[c]; \
  a0 = dot2f(gA.x, hv.x, a0); a1 = dot2f(gB.x, hv.x, a1); \
  b0 = dot2f(gA.y, hv.y, b0); b1 = dot2f(gB.y, hv.y, b1); \
  a0 = dot2f(gA.z, hv.z, a0); a1 = dot2f(gB.z, hv.z, a1); \
  b0 = dot2f(gA.w, hv.w, b0); b1 = dot2f(gB.w, hv.w, b1); }

#define DOTR(i)  DOT2(wA_##i, wB_##i, i)

__global__ __launch_bounds__(512, 1) void scan_kernel(ScanJob j0, ScanJob j1) {
  ScanJob j = (blockIdx.x < B_) ? j0 : j1;
  if (!j.valid) return;
  const int b = blockIdx.x & (B_ - 1);
  const int t = threadIdx.x;
  const int p = t & 255, s = t >> 8;
  const int r0 = p + s * 256;
  const int r1 = r0 + 512;

  __shared__ uint4 wmid[MC * 1024];                    // 147456 B
  __shared__ __align__(16) unsigned short hsm[256];    // h packed f16
  __shared__ float pig[256];                           // sigm(i)*tanh(g)

  const uint4* wall_p = j.wall;

  // stage LDS tier (chunks HC..31, coalesced)
#pragma unroll
  for (int i = 0; i < MC * 2; i++)
    wmid[i * 512 + t] = wall_p[HC * 1024 + i * 512 + t];

  // register tier: chunks 0..22, rows r0/r1 -> 184 dwords, pinned
  C23(LOADW)
  C23(PINW)

  float c_reg = 0.f, h_reg = 0.f, mk = 0.f;
  if (s == 1) {
    c_reg = j.cstate[b * 256 + p];
    mk    = j.mask[b * 256 + p];
  } else {
    hsm[p] = h16bits(j.hstate[b * 256 + p]);
  }
  __syncthreads();

  const uint4* hs4 = (const uint4*)hsm;
  const _Float16* xwb = j.xw + (long)b * TC * G4;
  float xA = (float)xwb[r0], xB = (float)xwb[r1];
  float hm_prev = 0.f;

  for (int tc = 0; tc < TC; ++tc) {
    // prefetch next step's xw
    float nA = 0.f, nB = 0.f;
    if (tc + 1 < TC) {
      nA = (float)xwb[(long)(tc + 1) * G4 + r0];
      nB = (float)xwb[(long)(tc + 1) * G4 + r1];
    }

    // deferred output store for previous step (drain hides under the dots)
    if (s == 1 && tc > 0) {
      if (j.ychunk) j.ychunk[(b * TC + tc - 1) * H_ + p] = (_Float16)hm_prev;
      else          j.out[(long)(b * T_ + j.t0 + tc - 1) * H_ + p] = hm_prev;
    }

    float a0 = xA, a1 = xB, b0 = 0.f, b1 = 0.f;

    // register tier (23 chunks)
    C23(DOTR)

    // LDS tier (9 chunks)
#pragma unroll
    for (int m = 0; m < MC; m++) {
      uint4 tA = wmid[m * 1024 + r0];
      uint4 tB = wmid[m * 1024 + r1];
      DOT2(tA, tB, HC + m)
    }

    float aF = a0 + b0;   // s=0: pre_i ; s=1: pre_f
    float bF = a1 + b1;   // s=0: pre_g ; s=1: pre_o

    if (s == 0) pig[p] = sigm(aF) * tanh_fast(bF);
    __syncthreads();
    if (s == 1) {
      c_reg = sigm(aF) * c_reg + pig[p];
      h_reg = sigm(bF) * tanh_fast(c_reg);
      hsm[p] = h16bits(h_reg);
      hm_prev = h_reg * mk;
    }
    xA = nA; xB = nB;
    __syncthreads();
  }

  if (s == 1) {
    if (j.ychunk) j.ychunk[(b * TC + TC - 1) * H_ + p] = (_Float16)hm_prev;
    else          j.out[(long)(b * T_ + j.t0 + TC - 1) * H_ + p] = hm_prev;
    j.hstate[b * 256 + p] = h_reg;
    j.cstate[b * 256 + p] = c_reg;
    if (j.hn) { j.hn[b * 256 + p] = h_reg; j.cn[b * 256 + p] = c_reg; }
  }
}

// ---------------- host launch ----------------
extern "C" void kernel_launch(void* const* d_in, const int* in_sizes, int n_in,
                              void* d_out, int out_size, void* d_ws, size_t ws_size,
                              hipStream_t stream) {
  const float* x     = (const float*)d_in[0];
  const float* Wih0  = (const float*)d_in[1];
  const float* Whh0  = (const float*)d_in[2];
  const float* bih0  = (const float*)d_in[3];
  const float* bhh0  = (const float*)d_in[4];
  const float* mask0 = (const float*)d_in[5];
  const float* Wih1  = (const float*)d_in[6];
  const float* Whh1  = (const float*)d_in[7];
  const float* bih1  = (const float*)d_in[8];
  const float* bhh1  = (const float*)d_in[9];
  const float* mask1 = (const float*)d_in[10];

  float* out = (float*)d_out;
  float* hn  = out + (long)B_ * T_ * H_;   // [2][64][256]
  float* cn  = hn + 2 * B_ * H_;

  char* w = (char*)d_ws;
  uint4*    wall0  = (uint4*)w;      w += 512 << 10;   // [32][1024] uint4
  uint4*    wall1  = (uint4*)w;      w += 512 << 10;
  _Float16* wf0    = (_Float16*)w;   w += 256 << 10;
  _Float16* wf1    = (_Float16*)w;   w += 512 << 10;
  float*    bias0  = (float*)w;      w += 4 << 10;
  float*    bias1  = (float*)w;      w += 4 << 10;
  float*    h0s    = (float*)w;      w += 64 << 10;
  float*    c0s    = (float*)w;      w += 64 << 10;
  float*    h1s    = (float*)w;      w += 64 << 10;
  float*    c1s    = (float*)w;      w += 64 << 10;
  _Float16* xw0    = (_Float16*)w;   w += (long)B_ * TC * G4 * 2;   // 16 MB
  _Float16* xw1    = (_Float16*)w;   w += (long)B_ * TC * G4 * 2;   // 16 MB
  _Float16* ybuf   = (_Float16*)w;   w += (long)B_ * TC * H_ * 2;   // 4 MB

  hipMemsetAsync(h0s, 0, 4 * (64 << 10), stream);

  prep_w<<<128, 256, 0, stream>>>(Whh0, wall0);
  prep_w<<<128, 256, 0, stream>>>(Whh1, wall1);
  prep_f16<<<512, 256, 0, stream>>>(Wih0, wf0, G4 * I_);
  prep_f16<<<1024, 256, 0, stream>>>(Wih1, wf1, G4 * H_);
  prep_bias<<<4, 256, 0, stream>>>(bih0, bhh0, bias0);
  prep_bias<<<4, 256, 0, stream>>>(bih1, bhh1, bias1);

  const int nchunk = T_ / TC;  // 16
  for (int k = 0; k <= nchunk; k++) {
    if (k < nchunk) {
      proj_kernel<I_, true><<<dim3(B_ * TC / 64, G4 / 64), 256, 0, stream>>>(
          x, wf0, bias0, xw0, k * TC);
    }
    ScanJob j0, j1;
    // layer 0, chunk k
    j0.xw = xw0; j0.wall = wall0; j0.mask = mask0;
    j0.hstate = h0s; j0.cstate = c0s;
    j0.ychunk = ybuf; j0.out = nullptr;
    j0.hn = (k == nchunk - 1) ? hn : nullptr;
    j0.cn = (k == nchunk - 1) ? cn : nullptr;
    j0.t0 = k * TC; j0.valid = (k < nchunk);
    // layer 1, chunk k-1
    j1.xw = xw1; j1.wall = wall1; j1.mask = mask1;
    j1.hstate = h1s; j1.cstate = c1s;
    j1.ychunk = nullptr; j1.out = out;
    j1.hn = (k == nchunk) ? hn + B_ * H_ : nullptr;
    j1.cn = (k == nchunk) ? cn + B_ * H_ : nullptr;
    j1.t0 = (k - 1) * TC; j1.valid = (k >= 1);

    scan_kernel<<<2 * B_, 512, 0, stream>>>(j0, j1);

    if (k < nchunk) {
      proj_kernel<H_, false><<<dim3(B_ * TC / 64, G4 / 64), 256, 0, stream>>>(
          ybuf, wf1, bias1, xw1, k * TC);
    }
  }
}